// Round 9
// baseline (164.437 us; speedup 1.0000x reference)
//
#include <hip/hip_runtime.h>

#define EDIM 1024
#define LSEQ 2048
#define NBATCH 2
#define NHEADS 16
#define HDIM 64
#define QSCALE 0.18033688011112042f  // log2(e)/8: exp(s/8) == exp2(s*QSCALE)

typedef unsigned short us;
typedef __attribute__((ext_vector_type(8))) short short8;
typedef __attribute__((ext_vector_type(4))) float floatx4;
typedef __attribute__((ext_vector_type(16))) float floatx16;

#define MFMA16(a, b, c) __builtin_amdgcn_mfma_f32_16x16x32_bf16((a), (b), (c), 0, 0, 0)
#define MFMA32(a, b, c) __builtin_amdgcn_mfma_f32_32x32x16_bf16((a), (b), (c), 0, 0, 0)
#define ZERO16 ((floatx16){0.f,0.f,0.f,0.f,0.f,0.f,0.f,0.f,0.f,0.f,0.f,0.f,0.f,0.f,0.f,0.f})

#define WAIT_VM8 asm volatile("s_waitcnt vmcnt(8)" ::: "memory")
#define WAIT_VM4 asm volatile("s_waitcnt vmcnt(4)" ::: "memory")
#define WAIT_VM0 asm volatile("s_waitcnt vmcnt(0)" ::: "memory")
#define WAIT_LGKM0 asm volatile("s_waitcnt lgkmcnt(0)" ::: "memory")
#define CFENCE asm volatile("" ::: "memory")

__device__ __forceinline__ us f2bf(float f) {
  unsigned int u = __float_as_uint(f);
  u += 0x7fffu + ((u >> 16) & 1u);
  return (us)(u >> 16);
}

__device__ __forceinline__ void gload16(const void* g, void* l) {
  __builtin_amdgcn_global_load_lds((const __attribute__((address_space(1))) unsigned int*)g,
                                   (__attribute__((address_space(3))) unsigned int*)l, 16, 0, 0);
}

__device__ __forceinline__ unsigned int cvtpk(float lo, float hi_) {
  unsigned int r;
  asm("v_cvt_pk_bf16_f32 %0, %1, %2" : "=v"(r) : "v"(lo), "v"(hi_));
  return r;
}
__device__ __forceinline__ void plswap(unsigned int& a, unsigned int& b) {
  asm("v_permlane32_swap_b32 %0, %1" : "+v"(a), "+v"(b));
}
__device__ __forceinline__ short8 mkfrag(unsigned int a, unsigned int b, unsigned int c,
                                         unsigned int d) {
  union { unsigned int u[4]; short8 v; } x;
  x.u[0] = a; x.u[1] = b; x.u[2] = c; x.u[3] = d;
  return x.v;
}
// acc (16 f32, rows crow(r,hi)) -> two PV A-fragments (k 0-15, k 16-31)
__device__ __forceinline__ void pack2(const floatx16 p, short8& f0, short8& f1) {
  unsigned int A = cvtpk(p[0], p[1]), B = cvtpk(p[4], p[5]); plswap(A, B);
  unsigned int C = cvtpk(p[2], p[3]), D = cvtpk(p[6], p[7]); plswap(C, D);
  f0 = mkfrag(A, C, B, D);
  unsigned int E = cvtpk(p[8], p[9]), F = cvtpk(p[12], p[13]); plswap(E, F);
  unsigned int G = cvtpk(p[10], p[11]), H = cvtpk(p[14], p[15]); plswap(G, H);
  f1 = mkfrag(E, G, F, H);
}

__device__ __forceinline__ short8 onesfrag() {
  union { us u[8]; short8 v; } x;
#pragma unroll
  for (int i = 0; i < 8; ++i) x.u[i] = 0x3F80;  // bf16 1.0
  return x.v;
}

// ---------------- fp32 -> bf16 bulk convert, all 7 tensors in one launch ----------------
__global__ void k_f2bf_all(const float* q, const float* k, const float* v,
                           const float* wq, const float* wk, const float* wv, const float* wo,
                           us* dq, us* dk, us* dv, us* dwq, us* dwk, us* dwv, us* dwo) {
  const int z = blockIdx.y;
  const float* s; us* d; int n8;
  if (z == 0)      { s = q;  d = dq;  n8 = 524288; }
  else if (z == 1) { s = k;  d = dk;  n8 = 524288; }
  else if (z == 2) { s = v;  d = dv;  n8 = 524288; }
  else if (z == 3) { s = wq; d = dwq; n8 = 131072; }
  else if (z == 4) { s = wk; d = dwk; n8 = 131072; }
  else if (z == 5) { s = wv; d = dwv; n8 = 131072; }
  else             { s = wo; d = dwo; n8 = 131072; }
  int i = blockIdx.x * blockDim.x + threadIdx.x;
  int stride = gridDim.x * blockDim.x;
  for (; i < n8; i += stride) {
    float4 a = ((const float4*)s)[2 * i];
    float4 b = ((const float4*)s)[2 * i + 1];
    union { us u[8]; uint4 vv; } o;
    o.u[0] = f2bf(a.x); o.u[1] = f2bf(a.y); o.u[2] = f2bf(a.z); o.u[3] = f2bf(a.w);
    o.u[4] = f2bf(b.x); o.u[5] = f2bf(b.y); o.u[6] = f2bf(b.z); o.u[7] = f2bf(b.w);
    ((uint4*)d)[i] = o.vv;
  }
}

// ------- GEMM: 128x128 tile, BK=32, 4 waves, 4x4 acc, counted-vmcnt depth-2 pipeline -------
// MODE 0: bf16 scatter [bh][seq][64]; MODE 1: bf16 -> Vt [bh][64][seq] via LDS transpose;
// MODE 2: fp32 direct.
template <int MODE>
__device__ __forceinline__ void gemm_core(us* pool,
                                          const us* __restrict__ A, const us* __restrict__ B,
                                          const float* __restrict__ bias, void* __restrict__ outp,
                                          int row0, int col0, float scale) {
  // double-buffered tiles: As[b]=[128][32], Bs[b]=[128][32]
  us* const Asb[2] = {pool, pool + 8192};
  us* const Bsb[2] = {pool + 4096, pool + 12288};
  const int t = threadIdx.x;
  const int w = t >> 6, lane = t & 63;
  const int g = lane >> 4, lr = lane & 15;
  const int wm = (w & 1) * 64, wn = (w >> 1) * 64;
  const int srow = lane >> 2, scol = (lane & 3) * 8;
  const int cA = 2 * w;
  const us* Asrc = A + (size_t)(row0 + cA * 16 + srow) * EDIM + scol;
  const us* Bsrc = B + (size_t)(col0 + cA * 16 + srow) * EDIM + scol;

  floatx4 acc[4][4];
#pragma unroll
  for (int mi = 0; mi < 4; ++mi)
#pragma unroll
    for (int ni = 0; ni < 4; ++ni) acc[mi][ni] = (floatx4){0.f, 0.f, 0.f, 0.f};

  // per wave per tile: 4 VMEM ops (2 A-chunks + 2 B-chunks)
  auto stage = [&](int kt, int b) {
    const int k0 = kt * 32;
    gload16(Asrc + k0, Asb[b] + cA * 512);
    gload16(Asrc + 16 * EDIM + k0, Asb[b] + cA * 512 + 512);
    gload16(Bsrc + k0, Bsb[b] + cA * 512);
    gload16(Bsrc + 16 * EDIM + k0, Bsb[b] + cA * 512 + 512);
  };

  stage(0, 0);
  stage(1, 1);  // 8 VMEM/wave in flight

  for (int kt = 0; kt < 32; ++kt) {
    if (kt < 31) { WAIT_VM4; } else { WAIT_VM0; }  // own tile-kt loads landed; keep t+1 in flight
    __builtin_amdgcn_s_barrier();                  // collective: tile kt fully resident
    CFENCE;
    const us* Ac = Asb[kt & 1];
    const us* Bc = Bsb[kt & 1];
    short8 af[4], bfr[4];
#pragma unroll
    for (int mi = 0; mi < 4; ++mi) af[mi] = *(const short8*)&Ac[(wm + mi * 16 + lr) * 32 + g * 8];
#pragma unroll
    for (int ni = 0; ni < 4; ++ni) bfr[ni] = *(const short8*)&Bc[(wn + ni * 16 + lr) * 32 + g * 8];
#pragma unroll
    for (int mi = 0; mi < 4; ++mi)
#pragma unroll
      for (int ni = 0; ni < 4; ++ni) acc[mi][ni] = MFMA16(af[mi], bfr[ni], acc[mi][ni]);
    WAIT_LGKM0;                                    // my ds_reads retired (data in regs)
    __builtin_amdgcn_s_barrier();                  // collective: buf[kt&1] reusable
    CFENCE;
    if (kt + 2 < 32) stage(kt + 2, kt & 1);
  }

  if (MODE == 1) {
    us* Ct = pool;  // 128*136 (aliases dbuf; safe: vmcnt drained, all reads done)
#pragma unroll
    for (int ni = 0; ni < 4; ++ni) {
      const int colloc = wn + ni * 16 + lr;
      const float bv = bias[col0 + colloc];
#pragma unroll
      for (int mi = 0; mi < 4; ++mi) {
        const int b = wm + mi * 16 + 4 * g;
        unsigned int lo = (unsigned int)f2bf(acc[mi][ni][0] + bv) |
                          ((unsigned int)f2bf(acc[mi][ni][2] + bv) << 16);
        unsigned int hi = (unsigned int)f2bf(acc[mi][ni][1] + bv) |
                          ((unsigned int)f2bf(acc[mi][ni][3] + bv) << 16);
        *(unsigned int*)&Ct[colloc * 136 + (b >> 1)] = lo;
        *(unsigned int*)&Ct[colloc * 136 + 64 + (b >> 1)] = hi;
      }
    }
    __syncthreads();
    const int rr = t >> 1, half = t & 1;
    const int c = col0 + rr, h = c >> 6, d = c & 63;
    us* dst = (us*)outp + (((size_t)half * NHEADS + h) * HDIM + d) * LSEQ + (row0 >> 1);
    const us* srcRow = &Ct[rr * 136 + half * 64];
#pragma unroll
    for (int j = 0; j < 8; ++j)
      *(uint4*)(dst + j * 8) = *(const uint4*)(srcRow + j * 8);
  } else {
#pragma unroll
    for (int ni = 0; ni < 4; ++ni) {
      const int col = col0 + wn + ni * 16 + lr;
      const float bv = bias[col];
#pragma unroll
      for (int mi = 0; mi < 4; ++mi) {
#pragma unroll
        for (int i = 0; i < 4; ++i) {
          const int row = row0 + wm + mi * 16 + g * 4 + i;
          const float v = (acc[mi][ni][i] + bv) * scale;
          if (MODE == 2) {
            ((float*)outp)[(size_t)row * EDIM + col] = v;
          } else {
            const int n = row & 1, sq = row >> 1;
            const int h = col >> 6, d = col & 63;
            ((us*)outp)[(((size_t)n * NHEADS + h) * LSEQ + sq) * HDIM + d] = f2bf(v);
          }
        }
      }
    }
  }
}

__global__ __launch_bounds__(256) void k_gemm_qkv(
    const us* __restrict__ Xq, const us* __restrict__ Xk, const us* __restrict__ Xv,
    const us* __restrict__ Wqb, const us* __restrict__ Wkb, const us* __restrict__ Wvb,
    const float* __restrict__ bq, const float* __restrict__ bk, const float* __restrict__ bv,
    us* __restrict__ qo, us* __restrict__ ko, us* __restrict__ vo) {
  __shared__ us pool[17408];
  const int z = blockIdx.z;
  if (z == 0)      gemm_core<0>(pool, Xq, Wqb, bq, qo, blockIdx.x * 128, blockIdx.y * 128, QSCALE);
  else if (z == 1) gemm_core<0>(pool, Xk, Wkb, bk, ko, blockIdx.x * 128, blockIdx.y * 128, 1.0f);
  else             gemm_core<1>(pool, Xv, Wvb, bv, vo, blockIdx.x * 128, blockIdx.y * 128, 1.0f);
}

__global__ __launch_bounds__(256) void k_gemm_o(const us* __restrict__ A, const us* __restrict__ B,
                                                const float* __restrict__ bias, float* __restrict__ out) {
  __shared__ us pool[16384];
  gemm_core<2>(pool, A, B, bias, out, blockIdx.x * 128, blockIdx.y * 128, 1.0f);
}

// ------- fused attention v2: 2-wave blocks (64 q/block), in-register P, MFMA-ones ell -------
// grid (bh=32, lblk=32), 128 thr. K/V 64x64 dbuf LDS, XOR-swizzled, counted vmcnt(8).
__global__ __launch_bounds__(128) void k_attn(const us* __restrict__ qb, const us* __restrict__ kb,
                                              const us* __restrict__ vt, float* __restrict__ rell,
                                              us* __restrict__ O) {
  __shared__ us Ks[2][4096];
  __shared__ us Vs[2][4096];
  const int bh = blockIdx.x;
  const int l0 = blockIdx.y * 64;
  const int t = threadIdx.x, w = t >> 6, lane = t & 63;
  const int ql = lane & 31, hi = lane >> 5;
  const int lbase = l0 + w * 32;

  // Q in registers: qf[dt] = Q[lbase+ql][dt*16 + hi*8 .. +8]  (B-operand layout)
  short8 qf[4];
  {
    const us* qptr = qb + ((size_t)bh * LSEQ + lbase + ql) * HDIM + hi * 8;
#pragma unroll
    for (int dt = 0; dt < 4; ++dt) qf[dt] = *(const short8*)(qptr + dt * 16);
  }

  // swizzled LDS read offsets (rows ql and 32+ql, chunk (2j+hi)^(row&7))
  int off0[4], off1[4];
#pragma unroll
  for (int j = 0; j < 4; ++j) {
    off0[j] = ql * 64 + (((2 * j + hi) ^ (ql & 7)) << 3);
    off1[j] = (32 + ql) * 64 + (((2 * j + hi) ^ (ql & 7)) << 3);
  }

  // staging: wave w covers 1KB chunks 4w..4w+3 of K and V (8 gload16/wave/tile)
  const int srA = lane >> 3;
  const int scA = ((lane & 7) ^ (lane >> 3)) * 8;
  const us* Kbase = kb + (size_t)bh * LSEQ * HDIM;
  const us* Vbase = vt + (size_t)bh * HDIM * LSEQ;
  const us* Ksrc[4];
  const us* Vsrc[4];
#pragma unroll
  for (int i = 0; i < 4; ++i) {
    const int jj = 4 * w + i;
    Ksrc[i] = Kbase + (jj * 8 + srA) * HDIM + scA;
    Vsrc[i] = Vbase + (size_t)(jj * 8 + srA) * LSEQ + scA;
  }

  floatx16 oacc0 = ZERO16, oacc1 = ZERO16, ellmf = ZERO16;
  const short8 onesf = onesfrag();

  auto stageKV = [&](int kt, int b) {
    const int so = kt * 64;
#pragma unroll
    for (int i = 0; i < 4; ++i) {
      gload16(Ksrc[i] + so * HDIM, &Ks[b][(4 * w + i) * 512]);
      gload16(Vsrc[i] + so, &Vs[b][(4 * w + i) * 512]);
    }
  };

  stageKV(0, 0);
  stageKV(1, 1);  // 16 VMEM/wave in flight

  for (int it = 0; it < 32; ++it) {
    if (it < 31) { WAIT_VM8; } else { WAIT_VM0; }
    __builtin_amdgcn_s_barrier();  // collective: tile it resident
    CFENCE;
    const us* Kc = Ks[it & 1];
    const us* Vc = Vs[it & 1];

    // S^T = K . Q^T : lane holds S[krow crow(r,hi)][qcol ql] for all 64 krows
    floatx16 acc0 = ZERO16, acc1 = ZERO16;
    __builtin_amdgcn_s_setprio(1);
#pragma unroll
    for (int dt = 0; dt < 4; ++dt) {
      acc0 = MFMA32(*(const short8*)&Kc[off0[dt]], qf[dt], acc0);
      acc1 = MFMA32(*(const short8*)&Kc[off1[dt]], qf[dt], acc1);
    }
    __builtin_amdgcn_s_setprio(0);
    // exp2 in place (Q pre-scaled by log2e/8)
#pragma unroll
    for (int r = 0; r < 16; ++r) {
      acc0[r] = __builtin_amdgcn_exp2f(acc0[r]);
      acc1[r] = __builtin_amdgcn_exp2f(acc1[r]);
    }
    // pack to PV A-fragments (k-slots 0..3 cover s-local 0..63)
    short8 pa0, pa1, pa2, pa3;
    pack2(acc0, pa0, pa1);
    pack2(acc1, pa2, pa3);
    // PV + ell (MFMA with ones B-frag: D[q][*] = sum_s P[q][s])
    __builtin_amdgcn_s_setprio(1);
#pragma unroll
    for (int dt2 = 0; dt2 < 2; ++dt2) {
      floatx16& oa = dt2 ? oacc1 : oacc0;
      const int* off = dt2 ? off1 : off0;
      oa = MFMA32(pa0, *(const short8*)&Vc[off[0]], oa);
      oa = MFMA32(pa1, *(const short8*)&Vc[off[1]], oa);
      oa = MFMA32(pa2, *(const short8*)&Vc[off[2]], oa);
      oa = MFMA32(pa3, *(const short8*)&Vc[off[3]], oa);
    }
    ellmf = MFMA32(pa0, onesf, ellmf);
    ellmf = MFMA32(pa1, onesf, ellmf);
    ellmf = MFMA32(pa2, onesf, ellmf);
    ellmf = MFMA32(pa3, onesf, ellmf);
    __builtin_amdgcn_s_setprio(0);
    WAIT_LGKM0;                    // my K/V ds_reads retired
    __builtin_amdgcn_s_barrier();  // collective: buf[it&1] reusable
    CFENCE;
    if (it + 2 < 32) stageKV(it + 2, it & 1);
  }

  // per-register epilogue: ellmf[r] = ell[q=crow(r,hi)] (same r-mapping as oacc)
  float rinv[16];
#pragma unroll
  for (int r = 0; r < 16; ++r) rinv[r] = 1.0f / ellmf[r];
  if (ql == 0) {
#pragma unroll
    for (int r = 0; r < 16; ++r) {
      const int q = (r & 3) + 8 * (r >> 2) + 4 * hi;
      rell[(size_t)bh * LSEQ + lbase + q] = rinv[r];
    }
  }
  const int n = bh >> 4, hh = bh & 15;
  us* obase = O + (size_t)n * EDIM + (size_t)hh * HDIM;
#pragma unroll
  for (int r = 0; r < 16; ++r) {
    const int q = (r & 3) + 8 * (r >> 2) + 4 * hi;
    const size_t l = lbase + q;
    obase[l * (NBATCH * EDIM) + ql] = f2bf(oacc0[r] * rinv[r]);
    obase[l * (NBATCH * EDIM) + 32 + ql] = f2bf(oacc1[r] * rinv[r]);
  }
}

// ---------------- weights (swapped): W[n][l][s] = mean_h exp2(s*) / ell ----------------
// grid (lblk=8, sblk=32, n=2), QBLK=64/wave. Per-lane 1/ell scalar; K LDS dbuf over heads.
__global__ __launch_bounds__(256, 2) void k_weights(const us* __restrict__ qb, const us* __restrict__ kb,
                                                    const float* __restrict__ rell,
                                                    float* __restrict__ Wout) {
  __shared__ us Ks[2][4096];
  const int l0 = blockIdx.x * 256;
  const int s0 = blockIdx.y * 64;
  const int n = blockIdx.z;
  const int t = threadIdx.x, w = t >> 6, lane = t & 63;
  const int ql = lane & 31, hi = lane >> 5;
  const int lbase = l0 + w * 64;
  const int j0 = 2 * w, j1 = 2 * w + 1;
  const int srA = lane >> 3;
  const int scA = ((lane & 7) ^ (lane >> 3)) * 8;
  const us* Kb0 = kb + ((size_t)(n * NHEADS) * LSEQ + s0 + j0 * 8 + srA) * HDIM + scA;
  const us* Kb1 = kb + ((size_t)(n * NHEADS) * LSEQ + s0 + j1 * 8 + srA) * HDIM + scA;

  int off0[4], off1[4];
#pragma unroll
  for (int j = 0; j < 4; ++j) {
    off0[j] = ql * 64 + (((2 * j + hi) ^ (ql & 7)) << 3);
    off1[j] = (32 + ql) * 64 + (((2 * j + hi) ^ (ql & 7)) << 3);
  }

  floatx16 wa00 = ZERO16, wa01 = ZERO16, wa10 = ZERO16, wa11 = ZERO16;

  gload16(Kb0, &Ks[0][j0 * 512]); gload16(Kb1, &Ks[0][j1 * 512]);

  // current-head Q fragments + 1/ell (per-lane scalars)
  short8 qc0[4], qc1[4];
  float rlc0, rlc1;
  {
    const us* qp0 = qb + ((size_t)(n * NHEADS) * LSEQ + lbase + ql) * HDIM + hi * 8;
    const us* qp1 = qp0 + 32 * HDIM;
#pragma unroll
    for (int dt = 0; dt < 4; ++dt) {
      qc0[dt] = *(const short8*)(qp0 + dt * 16);
      qc1[dt] = *(const short8*)(qp1 + dt * 16);
    }
    rlc0 = rell[(size_t)(n * NHEADS) * LSEQ + lbase + ql];
    rlc1 = rell[(size_t)(n * NHEADS) * LSEQ + lbase + 32 + ql];
  }
  __syncthreads();

  for (int h = 0; h < NHEADS; ++h) {
    const int cur = h & 1;
    short8 qn0[4], qn1[4];
    float rln0 = 0.f, rln1 = 0.f;
    if (h < NHEADS - 1) {
      us* Kn2 = Ks[cur ^ 1];
      gload16(Kb0 + (size_t)(h + 1) * LSEQ * HDIM, Kn2 + j0 * 512);
      gload16(Kb1 + (size_t)(h + 1) * LSEQ * HDIM, Kn2 + j1 * 512);
      const us* qp0 = qb + ((size_t)(n * NHEADS + h + 1) * LSEQ + lbase + ql) * HDIM + hi * 8;
      const us* qp1 = qp0 + 32 * HDIM;
#pragma unroll
      for (int dt = 0; dt < 4; ++dt) {
        qn0[dt] = *(const short8*)(qp0 + dt * 16);
        qn1[dt] = *(const short8*)(qp1 + dt * 16);
      }
      rln0 = rell[(size_t)(n * NHEADS + h + 1) * LSEQ + lbase + ql];
      rln1 = rell[(size_t)(n * NHEADS + h + 1) * LSEQ + lbase + 32 + ql];
    }
    const us* Kc = Ks[cur];
    short8 kf0[4], kf1[4];
#pragma unroll
    for (int dt = 0; dt < 4; ++dt) {
      kf0[dt] = *(const short8*)&Kc[off0[dt]];
      kf1[dt] = *(const short8*)&Kc[off1[dt]];
    }
    {
      floatx16 aA = ZERO16, aB = ZERO16;
#pragma unroll
      for (int dt = 0; dt < 4; ++dt) {
        aA = MFMA32(kf0[dt], qc0[dt], aA);
        aB = MFMA32(kf1[dt], qc0[dt], aB);
      }
#pragma unroll
      for (int r = 0; r < 16; ++r) {
        wa00[r] += __builtin_amdgcn_exp2f(aA[r]) * rlc0;
        wa01[r] += __builtin_amdgcn_exp2f(aB[r]) * rlc0;
      }
    }
    {
      floatx16 cA = ZERO16, cB = ZERO16;
#pragma unroll
      for (int dt = 0; dt < 4; ++dt) {
        cA = MFMA32(kf0[dt], qc1[dt], cA);
        cB = MFMA32(kf1[dt], qc1[dt], cB);
      }
#pragma unroll
      for (int r = 0; r < 16; ++r) {
        wa10[r] += __builtin_amdgcn_exp2f(cA[r]) * rlc1;
        wa11[r] += __builtin_amdgcn_exp2f(cB[r]) * rlc1;
      }
    }
#pragma unroll
    for (int dt = 0; dt < 4; ++dt) { qc0[dt] = qn0[dt]; qc1[dt] = qn1[dt]; }
    rlc0 = rln0; rlc1 = rln1;
    __syncthreads();
  }

  // write: lane owns rows q = lbase + qh*32 + ql; cols s = s0 + sh*32 + crow(r,hi)
  float* wb0 = Wout + (size_t)n * LSEQ * LSEQ + (size_t)(lbase + ql) * LSEQ + s0;
  float* wb1 = Wout + (size_t)n * LSEQ * LSEQ + (size_t)(lbase + 32 + ql) * LSEQ + s0;
#pragma unroll
  for (int r = 0; r < 16; ++r) {
    const int cr = (r & 3) + 8 * (r >> 2) + 4 * hi;
    wb0[cr] = wa00[r] * 0.0625f;
    wb0[32 + cr] = wa01[r] * 0.0625f;
    wb1[cr] = wa10[r] * 0.0625f;
    wb1[32 + cr] = wa11[r] * 0.0625f;
  }
}

extern "C" void kernel_launch(void* const* d_in, const int* in_sizes, int n_in,
                              void* d_out, int out_size, void* d_ws, size_t ws_size,
                              hipStream_t stream) {
  const float* query = (const float*)d_in[0];
  const float* key   = (const float*)d_in[1];
  const float* value = (const float*)d_in[2];
  const float* Wq = (const float*)d_in[3]; const float* bq = (const float*)d_in[4];
  const float* Wk = (const float*)d_in[5]; const float* bk = (const float*)d_in[6];
  const float* Wv = (const float*)d_in[7]; const float* bv = (const float*)d_in[8];
  const float* Wo = (const float*)d_in[9]; const float* bo = (const float*)d_in[10];

  const size_t MB = 1u << 20;
  char* ws = (char*)d_ws;
  us* Xq  = (us*)(ws + 0 * MB);
  us* Xk  = (us*)(ws + 8 * MB);
  us* Xv  = (us*)(ws + 16 * MB);
  us* Wqb = (us*)(ws + 24 * MB);
  us* Wkb = (us*)(ws + 26 * MB);
  us* Wvb = (us*)(ws + 28 * MB);
  us* Wob = (us*)(ws + 30 * MB);
  us* qbuf = (us*)(ws + 32 * MB);
  us* kbuf = (us*)(ws + 40 * MB);
  us* Vt   = (us*)(ws + 48 * MB);
  us* Obuf = (us*)(ws + 56 * MB);
  float* rell = (float*)(ws + 64 * MB);

  k_f2bf_all<<<dim3(256, 7), 256, 0, stream>>>(query, key, value, Wq, Wk, Wv, Wo,
                                               Xq, Xk, Xv, Wqb, Wkb, Wvb, Wob);

  k_gemm_qkv<<<dim3(32, 8, 3), 256, 0, stream>>>(Xq, Xk, Xv, Wqb, Wkb, Wvb, bq, bk, bv,
                                                 qbuf, kbuf, Vt);

  k_attn<<<dim3(32, 32), 128, 0, stream>>>(qbuf, kbuf, Vt, rell, Obuf);

  k_gemm_o<<<dim3(32, 8), 256, 0, stream>>>(Obuf, Wob, bo, (float*)d_out);
  k_weights<<<dim3(8, 32, 2), 256, 0, stream>>>(qbuf, kbuf, rell, (float*)d_out + 4194304);
}

// Round 10
// 156.394 us; speedup vs baseline: 1.0514x; 1.0514x over previous
//
#include <hip/hip_runtime.h>

#define EDIM 1024
#define LSEQ 2048
#define NBATCH 2
#define NHEADS 16
#define HDIM 64
#define QSCALE 0.18033688011112042f  // log2(e)/8: exp(s/8) == exp2(s*QSCALE)

typedef unsigned short us;
typedef __attribute__((ext_vector_type(8))) short short8;
typedef __attribute__((ext_vector_type(4))) float floatx4;
typedef __attribute__((ext_vector_type(16))) float floatx16;

#define MFMA16(a, b, c) __builtin_amdgcn_mfma_f32_16x16x32_bf16((a), (b), (c), 0, 0, 0)
#define MFMA32(a, b, c) __builtin_amdgcn_mfma_f32_32x32x16_bf16((a), (b), (c), 0, 0, 0)
#define ZERO16 ((floatx16){0.f,0.f,0.f,0.f,0.f,0.f,0.f,0.f,0.f,0.f,0.f,0.f,0.f,0.f,0.f,0.f})

#define WAIT_VM4 asm volatile("s_waitcnt vmcnt(4)" ::: "memory")
#define WAIT_VM0 asm volatile("s_waitcnt vmcnt(0)" ::: "memory")
#define WAIT_LGKM0 asm volatile("s_waitcnt lgkmcnt(0)" ::: "memory")
#define CFENCE asm volatile("" ::: "memory")

__device__ __forceinline__ us f2bf(float f) {
  unsigned int u = __float_as_uint(f);
  u += 0x7fffu + ((u >> 16) & 1u);
  return (us)(u >> 16);
}

__device__ __forceinline__ void gload16(const void* g, void* l) {
  __builtin_amdgcn_global_load_lds((const __attribute__((address_space(1))) unsigned int*)g,
                                   (__attribute__((address_space(3))) unsigned int*)l, 16, 0, 0);
}

__device__ __forceinline__ unsigned int cvtpk(float lo, float hi_) {
  unsigned int r;
  asm("v_cvt_pk_bf16_f32 %0, %1, %2" : "=v"(r) : "v"(lo), "v"(hi_));
  return r;
}
__device__ __forceinline__ void plswap(unsigned int& a, unsigned int& b) {
  asm("v_permlane32_swap_b32 %0, %1" : "+v"(a), "+v"(b));
}
__device__ __forceinline__ short8 mkfrag(unsigned int a, unsigned int b, unsigned int c,
                                         unsigned int d) {
  union { unsigned int u[4]; short8 v; } x;
  x.u[0] = a; x.u[1] = b; x.u[2] = c; x.u[3] = d;
  return x.v;
}
// acc (16 f32, rows crow(r,hi)) -> two PV A-fragments (k 0-15, k 16-31)
__device__ __forceinline__ void pack2(const floatx16 p, short8& f0, short8& f1) {
  unsigned int A = cvtpk(p[0], p[1]), B = cvtpk(p[4], p[5]); plswap(A, B);
  unsigned int C = cvtpk(p[2], p[3]), D = cvtpk(p[6], p[7]); plswap(C, D);
  f0 = mkfrag(A, C, B, D);
  unsigned int E = cvtpk(p[8], p[9]), F = cvtpk(p[12], p[13]); plswap(E, F);
  unsigned int G = cvtpk(p[10], p[11]), H = cvtpk(p[14], p[15]); plswap(G, H);
  f1 = mkfrag(E, G, F, H);
}

__device__ __forceinline__ short8 onesfrag() {
  union { us u[8]; short8 v; } x;
#pragma unroll
  for (int i = 0; i < 8; ++i) x.u[i] = 0x3F80;  // bf16 1.0
  return x.v;
}

// ---------------- fp32 -> bf16 bulk convert, all 7 tensors in one launch ----------------
__global__ void k_f2bf_all(const float* q, const float* k, const float* v,
                           const float* wq, const float* wk, const float* wv, const float* wo,
                           us* dq, us* dk, us* dv, us* dwq, us* dwk, us* dwv, us* dwo) {
  const int z = blockIdx.y;
  const float* s; us* d; int n8;
  if (z == 0)      { s = q;  d = dq;  n8 = 524288; }
  else if (z == 1) { s = k;  d = dk;  n8 = 524288; }
  else if (z == 2) { s = v;  d = dv;  n8 = 524288; }
  else if (z == 3) { s = wq; d = dwq; n8 = 131072; }
  else if (z == 4) { s = wk; d = dwk; n8 = 131072; }
  else if (z == 5) { s = wv; d = dwv; n8 = 131072; }
  else             { s = wo; d = dwo; n8 = 131072; }
  int i = blockIdx.x * blockDim.x + threadIdx.x;
  int stride = gridDim.x * blockDim.x;
  for (; i < n8; i += stride) {
    float4 a = ((const float4*)s)[2 * i];
    float4 b = ((const float4*)s)[2 * i + 1];
    union { us u[8]; uint4 vv; } o;
    o.u[0] = f2bf(a.x); o.u[1] = f2bf(a.y); o.u[2] = f2bf(a.z); o.u[3] = f2bf(a.w);
    o.u[4] = f2bf(b.x); o.u[5] = f2bf(b.y); o.u[6] = f2bf(b.z); o.u[7] = f2bf(b.w);
    ((uint4*)d)[i] = o.vv;
  }
}

// ------- GEMM: 128x128 tile, BK=32, 4 waves, 4x4 acc, counted-vmcnt depth-2 pipeline -------
// MODE 0: bf16 scatter [bh][seq][64]; MODE 1: bf16 -> Vt [bh][64][seq] via LDS transpose;
// MODE 2: fp32 direct.
template <int MODE>
__device__ __forceinline__ void gemm_core(us* pool,
                                          const us* __restrict__ A, const us* __restrict__ B,
                                          const float* __restrict__ bias, void* __restrict__ outp,
                                          int row0, int col0, float scale) {
  // double-buffered tiles: As[b]=[128][32], Bs[b]=[128][32]
  us* const Asb[2] = {pool, pool + 8192};
  us* const Bsb[2] = {pool + 4096, pool + 12288};
  const int t = threadIdx.x;
  const int w = t >> 6, lane = t & 63;
  const int g = lane >> 4, lr = lane & 15;
  const int wm = (w & 1) * 64, wn = (w >> 1) * 64;
  const int srow = lane >> 2, scol = (lane & 3) * 8;
  const int cA = 2 * w;
  const us* Asrc = A + (size_t)(row0 + cA * 16 + srow) * EDIM + scol;
  const us* Bsrc = B + (size_t)(col0 + cA * 16 + srow) * EDIM + scol;

  floatx4 acc[4][4];
#pragma unroll
  for (int mi = 0; mi < 4; ++mi)
#pragma unroll
    for (int ni = 0; ni < 4; ++ni) acc[mi][ni] = (floatx4){0.f, 0.f, 0.f, 0.f};

  // per wave per tile: 4 VMEM ops (2 A-chunks + 2 B-chunks)
  auto stage = [&](int kt, int b) {
    const int k0 = kt * 32;
    gload16(Asrc + k0, Asb[b] + cA * 512);
    gload16(Asrc + 16 * EDIM + k0, Asb[b] + cA * 512 + 512);
    gload16(Bsrc + k0, Bsb[b] + cA * 512);
    gload16(Bsrc + 16 * EDIM + k0, Bsb[b] + cA * 512 + 512);
  };

  stage(0, 0);
  stage(1, 1);  // 8 VMEM/wave in flight

  for (int kt = 0; kt < 32; ++kt) {
    if (kt < 31) { WAIT_VM4; } else { WAIT_VM0; }  // own tile-kt loads landed; keep t+1 in flight
    __builtin_amdgcn_s_barrier();                  // collective: tile kt fully resident
    CFENCE;
    const us* Ac = Asb[kt & 1];
    const us* Bc = Bsb[kt & 1];
    short8 af[4], bfr[4];
#pragma unroll
    for (int mi = 0; mi < 4; ++mi) af[mi] = *(const short8*)&Ac[(wm + mi * 16 + lr) * 32 + g * 8];
#pragma unroll
    for (int ni = 0; ni < 4; ++ni) bfr[ni] = *(const short8*)&Bc[(wn + ni * 16 + lr) * 32 + g * 8];
#pragma unroll
    for (int mi = 0; mi < 4; ++mi)
#pragma unroll
      for (int ni = 0; ni < 4; ++ni) acc[mi][ni] = MFMA16(af[mi], bfr[ni], acc[mi][ni]);
    WAIT_LGKM0;                                    // my ds_reads retired (data in regs)
    __builtin_amdgcn_s_barrier();                  // collective: buf[kt&1] reusable
    CFENCE;
    if (kt + 2 < 32) stage(kt + 2, kt & 1);
  }

  if (MODE == 1) {
    us* Ct = pool;  // 128*136 (aliases dbuf; safe: vmcnt drained, all reads done)
#pragma unroll
    for (int ni = 0; ni < 4; ++ni) {
      const int colloc = wn + ni * 16 + lr;
      const float bv = bias[col0 + colloc];
#pragma unroll
      for (int mi = 0; mi < 4; ++mi) {
        const int b = wm + mi * 16 + 4 * g;
        unsigned int lo = (unsigned int)f2bf(acc[mi][ni][0] + bv) |
                          ((unsigned int)f2bf(acc[mi][ni][2] + bv) << 16);
        unsigned int hi = (unsigned int)f2bf(acc[mi][ni][1] + bv) |
                          ((unsigned int)f2bf(acc[mi][ni][3] + bv) << 16);
        *(unsigned int*)&Ct[colloc * 136 + (b >> 1)] = lo;
        *(unsigned int*)&Ct[colloc * 136 + 64 + (b >> 1)] = hi;
      }
    }
    __syncthreads();
    const int rr = t >> 1, half = t & 1;
    const int c = col0 + rr, h = c >> 6, d = c & 63;
    us* dst = (us*)outp + (((size_t)half * NHEADS + h) * HDIM + d) * LSEQ + (row0 >> 1);
    const us* srcRow = &Ct[rr * 136 + half * 64];
#pragma unroll
    for (int j = 0; j < 8; ++j)
      *(uint4*)(dst + j * 8) = *(const uint4*)(srcRow + j * 8);
  } else {
#pragma unroll
    for (int ni = 0; ni < 4; ++ni) {
      const int col = col0 + wn + ni * 16 + lr;
      const float bv = bias[col];
#pragma unroll
      for (int mi = 0; mi < 4; ++mi) {
#pragma unroll
        for (int i = 0; i < 4; ++i) {
          const int row = row0 + wm + mi * 16 + g * 4 + i;
          const float v = (acc[mi][ni][i] + bv) * scale;
          if (MODE == 2) {
            ((float*)outp)[(size_t)row * EDIM + col] = v;
          } else {
            const int n = row & 1, sq = row >> 1;
            const int h = col >> 6, d = col & 63;
            ((us*)outp)[(((size_t)n * NHEADS + h) * LSEQ + sq) * HDIM + d] = f2bf(v);
          }
        }
      }
    }
  }
}

__global__ __launch_bounds__(256) void k_gemm_qkv(
    const us* __restrict__ Xq, const us* __restrict__ Xk, const us* __restrict__ Xv,
    const us* __restrict__ Wqb, const us* __restrict__ Wkb, const us* __restrict__ Wvb,
    const float* __restrict__ bq, const float* __restrict__ bk, const float* __restrict__ bv,
    us* __restrict__ qo, us* __restrict__ ko, us* __restrict__ vo) {
  __shared__ us pool[17408];
  const int z = blockIdx.z;
  if (z == 0)      gemm_core<0>(pool, Xq, Wqb, bq, qo, blockIdx.x * 128, blockIdx.y * 128, QSCALE);
  else if (z == 1) gemm_core<0>(pool, Xk, Wkb, bk, ko, blockIdx.x * 128, blockIdx.y * 128, 1.0f);
  else             gemm_core<1>(pool, Xv, Wvb, bv, vo, blockIdx.x * 128, blockIdx.y * 128, 1.0f);
}

__global__ __launch_bounds__(256) void k_gemm_o(const us* __restrict__ A, const us* __restrict__ B,
                                                const float* __restrict__ bias, float* __restrict__ out) {
  __shared__ us pool[16384];
  gemm_core<2>(pool, A, B, bias, out, blockIdx.x * 128, blockIdx.y * 128, 1.0f);
}

// ------- fused attention v3: R8 shape (4 waves, 32 q/wave), 4-buffer K/V, 1 barrier/iter,
//         in-register P, MFMA-ones ell. grid (bh=32, lblk=16), 256 thr. ----------------
__global__ __launch_bounds__(256) void k_attn(const us* __restrict__ qb, const us* __restrict__ kb,
                                              const us* __restrict__ vt, float* __restrict__ rell,
                                              us* __restrict__ O) {
  __shared__ us Ks[4][4096];
  __shared__ us Vs[4][4096];
  const int bh = blockIdx.x;
  const int l0 = blockIdx.y * 128;
  const int t = threadIdx.x, w = t >> 6, lane = t & 63;
  const int ql = lane & 31, hi = lane >> 5;
  const int lbase = l0 + w * 32;

  // Q in registers: qf[dt] = Q[lbase+ql][dt*16 + hi*8 .. +8]  (B-operand layout)
  short8 qf[4];
  {
    const us* qptr = qb + ((size_t)bh * LSEQ + lbase + ql) * HDIM + hi * 8;
#pragma unroll
    for (int dt = 0; dt < 4; ++dt) qf[dt] = *(const short8*)(qptr + dt * 16);
  }

  // swizzled LDS read offsets (rows ql and 32+ql, chunk (2j+hi)^(row&7))
  int off0[4], off1[4];
#pragma unroll
  for (int j = 0; j < 4; ++j) {
    off0[j] = ql * 64 + (((2 * j + hi) ^ (ql & 7)) << 3);
    off1[j] = (32 + ql) * 64 + (((2 * j + hi) ^ (ql & 7)) << 3);
  }

  const int j0 = 2 * w, j1 = 2 * w + 1;
  const int srA = lane >> 3;
  const int scA = ((lane & 7) ^ (lane >> 3)) * 8;
  const us* Kbase = kb + (size_t)bh * LSEQ * HDIM;
  const us* Vbase = vt + (size_t)bh * HDIM * LSEQ;
  const us* Ksrc0 = Kbase + (j0 * 8 + srA) * HDIM + scA;
  const us* Ksrc1 = Kbase + (j1 * 8 + srA) * HDIM + scA;
  const us* Vsrc0 = Vbase + (size_t)(j0 * 8 + srA) * LSEQ + scA;
  const us* Vsrc1 = Vbase + (size_t)(j1 * 8 + srA) * LSEQ + scA;

  floatx16 oacc0 = ZERO16, oacc1 = ZERO16, ellmf = ZERO16;
  const short8 onesf = onesfrag();

  // per wave per tile: 4 VMEM ops (2 K + 2 V)
  auto stageKV = [&](int kt, int b) {
    const int so = kt * 64;
    gload16(Ksrc0 + so * HDIM, &Ks[b][j0 * 512]);
    gload16(Ksrc1 + so * HDIM, &Ks[b][j1 * 512]);
    gload16(Vsrc0 + so, &Vs[b][j0 * 512]);
    gload16(Vsrc1 + so, &Vs[b][j1 * 512]);
  };

  stageKV(0, 0);
  stageKV(1, 1);  // 8 VMEM/wave in flight

  for (int it = 0; it < 32; ++it) {
    if (it < 31) { WAIT_VM4; } else { WAIT_VM0; }  // tile `it` landed; it+1 stays in flight
    __builtin_amdgcn_s_barrier();                  // single collective sync per iter
    CFENCE;
    // prefetch into buf[(it+2)&3]: last read at iter it-2, retired before barrier `it`
    if (it + 2 < 32) stageKV(it + 2, (it + 2) & 3);
    const us* Kc = Ks[it & 3];
    const us* Vc = Vs[it & 3];

    // S^T = K . Q^T : lane holds S[krow crow(r,hi)][qcol ql] for all 64 krows
    floatx16 acc0 = ZERO16, acc1 = ZERO16;
    __builtin_amdgcn_s_setprio(1);
#pragma unroll
    for (int dt = 0; dt < 4; ++dt) {
      acc0 = MFMA32(*(const short8*)&Kc[off0[dt]], qf[dt], acc0);
      acc1 = MFMA32(*(const short8*)&Kc[off1[dt]], qf[dt], acc1);
    }
    __builtin_amdgcn_s_setprio(0);
    // exp2 in place (Q pre-scaled by log2e/8)
#pragma unroll
    for (int r = 0; r < 16; ++r) {
      acc0[r] = __builtin_amdgcn_exp2f(acc0[r]);
      acc1[r] = __builtin_amdgcn_exp2f(acc1[r]);
    }
    // pack to PV A-fragments (k-slots 0..3 cover s-local 0..63)
    short8 pa0, pa1, pa2, pa3;
    pack2(acc0, pa0, pa1);
    pack2(acc1, pa2, pa3);
    // PV + ell (MFMA with ones B-frag: D[q][*] = sum_s P[q][s])
    __builtin_amdgcn_s_setprio(1);
#pragma unroll
    for (int dt2 = 0; dt2 < 2; ++dt2) {
      floatx16& oa = dt2 ? oacc1 : oacc0;
      const int* off = dt2 ? off1 : off0;
      oa = MFMA32(pa0, *(const short8*)&Vc[off[0]], oa);
      oa = MFMA32(pa1, *(const short8*)&Vc[off[1]], oa);
      oa = MFMA32(pa2, *(const short8*)&Vc[off[2]], oa);
      oa = MFMA32(pa3, *(const short8*)&Vc[off[3]], oa);
    }
    ellmf = MFMA32(pa0, onesf, ellmf);
    ellmf = MFMA32(pa1, onesf, ellmf);
    ellmf = MFMA32(pa2, onesf, ellmf);
    ellmf = MFMA32(pa3, onesf, ellmf);
    __builtin_amdgcn_s_setprio(0);
    // no lgkm drain, no second barrier: 4-buffer rotation guarantees safety
  }

  // per-register epilogue: ellmf[r] = ell[q=crow(r,hi)] (same r-mapping as oacc)
  float rinv[16];
#pragma unroll
  for (int r = 0; r < 16; ++r) rinv[r] = 1.0f / ellmf[r];
  if (ql == 0) {
#pragma unroll
    for (int r = 0; r < 16; ++r) {
      const int q = (r & 3) + 8 * (r >> 2) + 4 * hi;
      rell[(size_t)bh * LSEQ + lbase + q] = rinv[r];
    }
  }
  const int n = bh >> 4, hh = bh & 15;
  us* obase = O + (size_t)n * EDIM + (size_t)hh * HDIM;
#pragma unroll
  for (int r = 0; r < 16; ++r) {
    const int q = (r & 3) + 8 * (r >> 2) + 4 * hi;
    const size_t l = lbase + q;
    obase[l * (NBATCH * EDIM) + ql] = f2bf(oacc0[r] * rinv[r]);
    obase[l * (NBATCH * EDIM) + 32 + ql] = f2bf(oacc1[r] * rinv[r]);
  }
}

// ---------------- weights (swapped): W[n][l][s] = mean_h exp2(s*) / ell ----------------
// grid (lblk=8, sblk=32, n=2), QBLK=64/wave. Per-lane 1/ell scalar; K LDS dbuf over heads.
__global__ __launch_bounds__(256, 2) void k_weights(const us* __restrict__ qb, const us* __restrict__ kb,
                                                    const float* __restrict__ rell,
                                                    float* __restrict__ Wout) {
  __shared__ us Ks[2][4096];
  const int l0 = blockIdx.x * 256;
  const int s0 = blockIdx.y * 64;
  const int n = blockIdx.z;
  const int t = threadIdx.x, w = t >> 6, lane = t & 63;
  const int ql = lane & 31, hi = lane >> 5;
  const int lbase = l0 + w * 64;
  const int j0 = 2 * w, j1 = 2 * w + 1;
  const int srA = lane >> 3;
  const int scA = ((lane & 7) ^ (lane >> 3)) * 8;
  const us* Kb0 = kb + ((size_t)(n * NHEADS) * LSEQ + s0 + j0 * 8 + srA) * HDIM + scA;
  const us* Kb1 = kb + ((size_t)(n * NHEADS) * LSEQ + s0 + j1 * 8 + srA) * HDIM + scA;

  int off0[4], off1[4];
#pragma unroll
  for (int j = 0; j < 4; ++j) {
    off0[j] = ql * 64 + (((2 * j + hi) ^ (ql & 7)) << 3);
    off1[j] = (32 + ql) * 64 + (((2 * j + hi) ^ (ql & 7)) << 3);
  }

  floatx16 wa00 = ZERO16, wa01 = ZERO16, wa10 = ZERO16, wa11 = ZERO16;

  gload16(Kb0, &Ks[0][j0 * 512]); gload16(Kb1, &Ks[0][j1 * 512]);

  // current-head Q fragments + 1/ell (per-lane scalars)
  short8 qc0[4], qc1[4];
  float rlc0, rlc1;
  {
    const us* qp0 = qb + ((size_t)(n * NHEADS) * LSEQ + lbase + ql) * HDIM + hi * 8;
    const us* qp1 = qp0 + 32 * HDIM;
#pragma unroll
    for (int dt = 0; dt < 4; ++dt) {
      qc0[dt] = *(const short8*)(qp0 + dt * 16);
      qc1[dt] = *(const short8*)(qp1 + dt * 16);
    }
    rlc0 = rell[(size_t)(n * NHEADS) * LSEQ + lbase + ql];
    rlc1 = rell[(size_t)(n * NHEADS) * LSEQ + lbase + 32 + ql];
  }
  __syncthreads();

  for (int h = 0; h < NHEADS; ++h) {
    const int cur = h & 1;
    short8 qn0[4], qn1[4];
    float rln0 = 0.f, rln1 = 0.f;
    if (h < NHEADS - 1) {
      us* Kn2 = Ks[cur ^ 1];
      gload16(Kb0 + (size_t)(h + 1) * LSEQ * HDIM, Kn2 + j0 * 512);
      gload16(Kb1 + (size_t)(h + 1) * LSEQ * HDIM, Kn2 + j1 * 512);
      const us* qp0 = qb + ((size_t)(n * NHEADS + h + 1) * LSEQ + lbase + ql) * HDIM + hi * 8;
      const us* qp1 = qp0 + 32 * HDIM;
#pragma unroll
      for (int dt = 0; dt < 4; ++dt) {
        qn0[dt] = *(const short8*)(qp0 + dt * 16);
        qn1[dt] = *(const short8*)(qp1 + dt * 16);
      }
      rln0 = rell[(size_t)(n * NHEADS + h + 1) * LSEQ + lbase + ql];
      rln1 = rell[(size_t)(n * NHEADS + h + 1) * LSEQ + lbase + 32 + ql];
    }
    const us* Kc = Ks[cur];
    short8 kf0[4], kf1[4];
#pragma unroll
    for (int dt = 0; dt < 4; ++dt) {
      kf0[dt] = *(const short8*)&Kc[off0[dt]];
      kf1[dt] = *(const short8*)&Kc[off1[dt]];
    }
    {
      floatx16 aA = ZERO16, aB = ZERO16;
#pragma unroll
      for (int dt = 0; dt < 4; ++dt) {
        aA = MFMA32(kf0[dt], qc0[dt], aA);
        aB = MFMA32(kf1[dt], qc0[dt], aB);
      }
#pragma unroll
      for (int r = 0; r < 16; ++r) {
        wa00[r] += __builtin_amdgcn_exp2f(aA[r]) * rlc0;
        wa01[r] += __builtin_amdgcn_exp2f(aB[r]) * rlc0;
      }
    }
    {
      floatx16 cA = ZERO16, cB = ZERO16;
#pragma unroll
      for (int dt = 0; dt < 4; ++dt) {
        cA = MFMA32(kf0[dt], qc1[dt], cA);
        cB = MFMA32(kf1[dt], qc1[dt], cB);
      }
#pragma unroll
      for (int r = 0; r < 16; ++r) {
        wa10[r] += __builtin_amdgcn_exp2f(cA[r]) * rlc1;
        wa11[r] += __builtin_amdgcn_exp2f(cB[r]) * rlc1;
      }
    }
#pragma unroll
    for (int dt = 0; dt < 4; ++dt) { qc0[dt] = qn0[dt]; qc1[dt] = qn1[dt]; }
    rlc0 = rln0; rlc1 = rln1;
    __syncthreads();
  }

  // write: lane owns rows q = lbase + qh*32 + ql; cols s = s0 + sh*32 + crow(r,hi)
  float* wb0 = Wout + (size_t)n * LSEQ * LSEQ + (size_t)(lbase + ql) * LSEQ + s0;
  float* wb1 = Wout + (size_t)n * LSEQ * LSEQ + (size_t)(lbase + 32 + ql) * LSEQ + s0;
#pragma unroll
  for (int r = 0; r < 16; ++r) {
    const int cr = (r & 3) + 8 * (r >> 2) + 4 * hi;
    wb0[cr] = wa00[r] * 0.0625f;
    wb0[32 + cr] = wa01[r] * 0.0625f;
    wb1[cr] = wa10[r] * 0.0625f;
    wb1[32 + cr] = wa11[r] * 0.0625f;
  }
}

extern "C" void kernel_launch(void* const* d_in, const int* in_sizes, int n_in,
                              void* d_out, int out_size, void* d_ws, size_t ws_size,
                              hipStream_t stream) {
  const float* query = (const float*)d_in[0];
  const float* key   = (const float*)d_in[1];
  const float* value = (const float*)d_in[2];
  const float* Wq = (const float*)d_in[3]; const float* bq = (const float*)d_in[4];
  const float* Wk = (const float*)d_in[5]; const float* bk = (const float*)d_in[6];
  const float* Wv = (const float*)d_in[7]; const float* bv = (const float*)d_in[8];
  const float* Wo = (const float*)d_in[9]; const float* bo = (const float*)d_in[10];

  const size_t MB = 1u << 20;
  char* ws = (char*)d_ws;
  us* Xq  = (us*)(ws + 0 * MB);
  us* Xk  = (us*)(ws + 8 * MB);
  us* Xv  = (us*)(ws + 16 * MB);
  us* Wqb = (us*)(ws + 24 * MB);
  us* Wkb = (us*)(ws + 26 * MB);
  us* Wvb = (us*)(ws + 28 * MB);
  us* Wob = (us*)(ws + 30 * MB);
  us* qbuf = (us*)(ws + 32 * MB);
  us* kbuf = (us*)(ws + 40 * MB);
  us* Vt   = (us*)(ws + 48 * MB);
  us* Obuf = (us*)(ws + 56 * MB);
  float* rell = (float*)(ws + 64 * MB);

  k_f2bf_all<<<dim3(256, 7), 256, 0, stream>>>(query, key, value, Wq, Wk, Wv, Wo,
                                               Xq, Xk, Xv, Wqb, Wkb, Wvb, Wob);

  k_gemm_qkv<<<dim3(32, 8, 3), 256, 0, stream>>>(Xq, Xk, Xv, Wqb, Wkb, Wvb, bq, bk, bv,
                                                 qbuf, kbuf, Vt);

  k_attn<<<dim3(32, 16), 256, 0, stream>>>(qbuf, kbuf, Vt, rell, Obuf);

  k_gemm_o<<<dim3(32, 8), 256, 0, stream>>>(Obuf, Wob, bo, (float*)d_out);
  k_weights<<<dim3(8, 32, 2), 256, 0, stream>>>(qbuf, kbuf, rell, (float*)d_out + 4194304);
}